// Round 2
// 326.202 us; speedup vs baseline: 1.0214x; 1.0214x over previous
//
#include <hip/hip_runtime.h>
#include <hip/hip_bf16.h>

#define SEQ_T 784
#define HID   128
#define S_H   152   // h-plane stride in shorts: 76 dwords == 12 mod 32 -> 2-way max on reads; 304B = 16B-aligned

typedef __attribute__((ext_vector_type(8))) short  short8;
typedef __attribute__((ext_vector_type(4))) float  floatx4;
typedef __attribute__((ext_vector_type(8))) float  float8;

// bf16 round-to-nearest-even on raw bits (inputs finite)
static __device__ __forceinline__ short bf16_of(float f) {
  union { float f; unsigned u; } v; v.f = f;
  return (short)((v.u + 0x7fffu + ((v.u >> 16) & 1u)) >> 16);
}

#define MFMA_BF16 __builtin_amdgcn_mfma_f32_16x16x32_bf16

// 256 blocks x 4 batch rows (1 block/CU). Per-step budget (measured R10: 925
// CU-cyc/step): MFMA pipe 466 (96 x 4.85, hard floor for the 128-col all-to-all
// recurrence), LDS ~250, gate VALU ~140, write+barrier ~150 -- phases run
// nearly serial (MfmaUtil 43 + VALUBusy 43, additive). R11 overlap surgery:
//  - Z-hoisted accumulator init (no per-step accvgpr zeroing)
//  - MFMA order: 6 first-halves then 6 second-halves; r,z finish early, n last
//    -> sigmoid VALU overlaps n-chain drain
//  - setprio(1) around the burst: leading wave exits to VALU while trailing
//    wave owns the matrix pipe (remove if regression, cf. m190 lockstep null)
//  - h written as packed bf16x2 b32 on even lanes (DPP 0xB1 neighbor +
//    v_cvt_pk_bf16_f32): conflict-free write banks, 1-op RNE convert
extern "C" __global__ void __launch_bounds__(512, 2)
gru_sparse4_t(const float* __restrict__ x,    // [1024][784] fp32
              const float* __restrict__ Wi,   // [384]
              const float* __restrict__ bi,   // [384]
              const float* __restrict__ Wh,   // [384][128]
              const float* __restrict__ bh,   // [384]
              const float* __restrict__ Wfc,  // [10][128]
              const float* __restrict__ bfc,  // [10]
              float* __restrict__ out)        // [1024][10] fp32
{
  const int tid  = threadIdx.x;
  const int wv   = tid >> 6;
  const int lane = tid & 63;
  const int quad = lane >> 4;
  const int nn   = lane & 15;
  const int j    = (wv << 4) | nn;   // this lane's hidden column
  const int b0   = blockIdx.x * 4;   // 4 batch rows per block

  __shared__ __align__(16) float xs[SEQ_T][4];      // x fp32, [t][row]
  __shared__ __align__(16) short hb[2][16 * S_H];   // h bf16, A-layout, dbuf
  __shared__ float hfin[4][HID];

  for (int i = tid; i < 2 * 16 * S_H; i += 512) ((short*)hb)[i] = 0;
  for (int i = tid; i < 4 * SEQ_T; i += 512) {
    const int r = i / SEQ_T;
    const int t = i - r * SEQ_T;
    xs[t][r] = x[(size_t)(b0 + r) * SEQ_T + t];
  }

  // fp32 per-column gate constants; fold bi+bh for r,z
  const float wi_r = Wi[j],  wi_z = Wi[HID + j],  wi_n = Wi[2 * HID + j];
  const float c_r  = bi[j] + bh[j];
  const float c_z  = bi[HID + j] + bh[HID + j];
  const float bi_n = bi[2 * HID + j];
  const float bh_n = bh[2 * HID + j];

  // Wh B-fragments, bf16 single-pass, register-resident.
  // Lane (quad,nn): B[k = kk*32 + quad*8 + e][n = nn] = Wh[j][k]
  short8 whi[3][4];
  #pragma unroll
  for (int g = 0; g < 3; ++g) {
    const float* wrow = Wh + (size_t)(g * HID + j) * HID;
    #pragma unroll
    for (int kk = 0; kk < 4; ++kk) {
      float8 w = *(const float8*)(wrow + kk * 32 + quad * 8);
      short8 hi;
      #pragma unroll
      for (int e = 0; e < 8; ++e) hi[e] = bf16_of(w[e]);
      whi[g][kk] = hi;
    }
  }

  float h = 0.0f;                          // h[batch=quad][j], fp32 carry
  const int a_off = nn * S_H + quad * 8;   // + kk*32 (shorts): A[m=nn][k]
  const int w_off = (quad * 4) * S_H + j;  // batch row quad at A-row 4*quad
  const bool wlane = ((nn & 1) == 0);      // even column -> owns the b32 store

  __syncthreads();

  const floatx4 Z = {0.f, 0.f, 0.f, 0.f}; // loop-invariant MFMA C-in

  auto step = [&](const short* __restrict__ hc, short* __restrict__ nx,
                  float xt) {
    short8 ah[4];
    #pragma unroll
    for (int kk = 0; kk < 4; ++kk)
      ah[kk] = *(const short8*)(hc + a_off + kk * 32);  // pad rows are zero

    // six chains, first-halves then second-halves (dep gap 6); n issues last
    __builtin_amdgcn_s_setprio(1);
    floatx4 r0 = MFMA_BF16(ah[0], whi[0][0], Z, 0, 0, 0);
    floatx4 r1 = MFMA_BF16(ah[1], whi[0][1], Z, 0, 0, 0);
    floatx4 z0 = MFMA_BF16(ah[0], whi[1][0], Z, 0, 0, 0);
    floatx4 z1 = MFMA_BF16(ah[1], whi[1][1], Z, 0, 0, 0);
    floatx4 n0 = MFMA_BF16(ah[0], whi[2][0], Z, 0, 0, 0);
    floatx4 n1 = MFMA_BF16(ah[1], whi[2][1], Z, 0, 0, 0);
    r0 = MFMA_BF16(ah[2], whi[0][2], r0, 0, 0, 0);
    r1 = MFMA_BF16(ah[3], whi[0][3], r1, 0, 0, 0);
    z0 = MFMA_BF16(ah[2], whi[1][2], z0, 0, 0, 0);
    z1 = MFMA_BF16(ah[3], whi[1][3], z1, 0, 0, 0);
    n0 = MFMA_BF16(ah[2], whi[2][2], n0, 0, 0, 0);
    n1 = MFMA_BF16(ah[3], whi[2][3], n1, 0, 0, 0);
    __builtin_amdgcn_s_setprio(0);

    // C reg 0 = batch row quad, column j. r,z sigmoids overlap n-chain drain.
    const float pr = fmaf(xt, wi_r, c_r) + (r0[0] + r1[0]);
    const float pz = fmaf(xt, wi_z, c_z) + (z0[0] + z1[0]);
    const float rg = __builtin_amdgcn_rcpf(1.0f + __expf(-pr));
    const float zg = __builtin_amdgcn_rcpf(1.0f + __expf(-pz));
    const float pn = fmaf(rg, (n0[0] + n1[0]) + bh_n, fmaf(xt, wi_n, bi_n));
    const float ng = 1.0f - 2.0f * __builtin_amdgcn_rcpf(1.0f + __expf(2.0f * pn));
    h = fmaf(zg, h - ng, ng);          // z*h + (1-z)*n

    // packed bf16x2 store: DPP quad_perm [1,0,3,2] brings neighbor col's h;
    // cvt_pk (RNE, == bf16_of) packs [j | j+1]; even lanes store one dword.
    // Even-lane write banks: quad*24 + wv*8 + nn/2 -> all 32, conflict-free.
    const float hnb = __int_as_float(
        __builtin_amdgcn_mov_dpp(__float_as_int(h), 0xB1, 0xF, 0xF, true));
    int hp;
    asm("v_cvt_pk_bf16_f32 %0, %1, %2" : "=v"(hp) : "v"(h), "v"(hnb));
    if (wlane) *(int*)(nx + w_off) = hp;
  };

  for (int t = 0; t < SEQ_T; t += 2) {
    const float xa = xs[t][quad];       // hoisted off the critical path
    const float xb = xs[t + 1][quad];   // xs is read-only in the loop
    step(hb[0], hb[1], xa);
    __syncthreads();
    step(hb[1], hb[0], xb);
    __syncthreads();
  }

  // epilogue: logits = h @ Wfc^T + bfc (fp32), 4 rows x 10 outs
  hfin[quad][j] = h;
  __syncthreads();
  if (tid < 40) {
    const int r = tid / 10, o = tid - r * 10;
    float acc = bfc[o];
    #pragma unroll 4
    for (int k = 0; k < HID; ++k)
      acc = fmaf(hfin[r][k], Wfc[o * HID + k], acc);
    out[(size_t)(b0 + r) * 10 + o] = acc;
  }
}

extern "C" void kernel_launch(void* const* d_in, const int* in_sizes, int n_in,
                              void* d_out, int out_size, void* d_ws, size_t ws_size,
                              hipStream_t stream) {
  const float* x   = (const float*)d_in[0];
  const float* Wi  = (const float*)d_in[1];
  const float* bi  = (const float*)d_in[2];
  const float* Wh  = (const float*)d_in[3];
  const float* bh  = (const float*)d_in[4];
  const float* Wfc = (const float*)d_in[5];
  const float* bfc = (const float*)d_in[6];
  hipLaunchKernelGGL(gru_sparse4_t, dim3(256), dim3(512), 0, stream,
                     x, Wi, bi, Wh, bh, Wfc, bfc, (float*)d_out);
}

// Round 3
// 325.392 us; speedup vs baseline: 1.0239x; 1.0025x over previous
//
#include <hip/hip_runtime.h>
#include <hip/hip_bf16.h>

#define SEQ_T 784
#define HID   128
#define S_H   160   // 4-row h-plane stride in shorts (320B): r*80 dwords == {0,16} mod 32
                    // -> read lanes land 2-per-bank-window (free); 16B-aligned

typedef __attribute__((ext_vector_type(8))) short  short8;
typedef __attribute__((ext_vector_type(4))) float  floatx4;
typedef __attribute__((ext_vector_type(8))) float  float8;

// bf16 round-to-nearest-even on raw bits (inputs finite)
static __device__ __forceinline__ short bf16_of(float f) {
  union { float f; unsigned u; } v; v.f = f;
  return (short)((v.u + 0x7fffu + ((v.u >> 16) & 1u)) >> 16);
}

#define MFMA_BF16 __builtin_amdgcn_mfma_f32_16x16x32_bf16

// 256 blocks x 4 batch rows (1 block/CU). R11 post-mortem: ALL 2.58e7 bank
// conflicts were on the A-tile ds_read_b128s (write packing moved the counter
// by zero). Root cause: 12 of 16 A-rows are structural zeros, re-read from LDS
// every step -> 32KB/step of LDS reads (~510 cyc, > the 466-cyc MFMA floor).
// R12: exec-masked A-loads. Only lanes nn&3==0 read (batch row nn>>2); all
// other lanes' ah registers are zeroed ONCE before the t-loop and never
// touched again (masked ds_read leaves inactive lanes intact). 4x less read
// traffic, 4-row h-plane, stride 160 -> 2-way banks everywhere (free, m136).
//  - Z-hoisted accumulator init; 6 first-half then 6 second-half MFMA order
//  - setprio(1) around the burst
//  - h written as packed bf16x2 b32 on even lanes (DPP 0xB1 + cvt_pk, RNE)
extern "C" __global__ void __launch_bounds__(512, 2)
gru_sparse4_t(const float* __restrict__ x,    // [1024][784] fp32
              const float* __restrict__ Wi,   // [384]
              const float* __restrict__ bi,   // [384]
              const float* __restrict__ Wh,   // [384][128]
              const float* __restrict__ bh,   // [384]
              const float* __restrict__ Wfc,  // [10][128]
              const float* __restrict__ bfc,  // [10]
              float* __restrict__ out)        // [1024][10] fp32
{
  const int tid  = threadIdx.x;
  const int wv   = tid >> 6;
  const int lane = tid & 63;
  const int quad = lane >> 4;
  const int nn   = lane & 15;
  const int j    = (wv << 4) | nn;   // this lane's hidden column
  const int b0   = blockIdx.x * 4;   // 4 batch rows per block

  __shared__ __align__(16) float xs[SEQ_T][4];     // x fp32, [t][row]
  __shared__ __align__(16) short hb[2][4 * S_H];   // h bf16, 4 real rows, dbuf
  __shared__ float hfin[4][HID];

  for (int i = tid; i < 2 * 4 * S_H; i += 512) ((short*)hb)[i] = 0;
  for (int i = tid; i < 4 * SEQ_T; i += 512) {
    const int r = i / SEQ_T;
    const int t = i - r * SEQ_T;
    xs[t][r] = x[(size_t)(b0 + r) * SEQ_T + t];
  }

  // fp32 per-column gate constants; fold bi+bh for r,z
  const float wi_r = Wi[j],  wi_z = Wi[HID + j],  wi_n = Wi[2 * HID + j];
  const float c_r  = bi[j] + bh[j];
  const float c_z  = bi[HID + j] + bh[HID + j];
  const float bi_n = bi[2 * HID + j];
  const float bh_n = bh[2 * HID + j];

  // Wh B-fragments, bf16 single-pass, register-resident.
  // Lane (quad,nn): B[k = kk*32 + quad*8 + e][n = nn] = Wh[j][k]
  short8 whi[3][4];
  #pragma unroll
  for (int g = 0; g < 3; ++g) {
    const float* wrow = Wh + (size_t)(g * HID + j) * HID;
    #pragma unroll
    for (int kk = 0; kk < 4; ++kk) {
      float8 w = *(const float8*)(wrow + kk * 32 + quad * 8);
      short8 hi;
      #pragma unroll
      for (int e = 0; e < 8; ++e) hi[e] = bf16_of(w[e]);
      whi[g][kk] = hi;
    }
  }

  float h = 0.0f;                          // h[batch=quad][j], fp32 carry
  // A[m=nn][k]: only rows nn&3==0 are real (batch row nn>>2, stored at that
  // LDS row). Read lanes: addr = (nn>>2)*S_H + quad*8 + kk*32 shorts.
  const bool rlane = ((nn & 3) == 0);
  const int a_off  = (nn >> 2) * S_H + quad * 8;
  const int w_off  = quad * S_H + j;       // batch row quad at LDS row quad
  const bool wlane = ((nn & 1) == 0);      // even column -> owns the b32 store

  __syncthreads();

  const floatx4 Z = {0.f, 0.f, 0.f, 0.f}; // loop-invariant MFMA C-in

  // A-fragments: zero-init ONCE; masked loads leave non-read lanes at zero.
  short8 ah0 = {0,0,0,0,0,0,0,0}, ah1 = ah0, ah2 = ah0, ah3 = ah0;

  auto step = [&](const short* __restrict__ hc, short* __restrict__ nx,
                  float xt) {
    if (rlane) {                            // 16 lanes/wave: 256B per read
      ah0 = *(const short8*)(hc + a_off);
      ah1 = *(const short8*)(hc + a_off + 32);
      ah2 = *(const short8*)(hc + a_off + 64);
      ah3 = *(const short8*)(hc + a_off + 96);
    }

    // six chains, first-halves then second-halves (dep gap 6); n issues last
    __builtin_amdgcn_s_setprio(1);
    floatx4 r0 = MFMA_BF16(ah0, whi[0][0], Z, 0, 0, 0);
    floatx4 r1 = MFMA_BF16(ah1, whi[0][1], Z, 0, 0, 0);
    floatx4 z0 = MFMA_BF16(ah0, whi[1][0], Z, 0, 0, 0);
    floatx4 z1 = MFMA_BF16(ah1, whi[1][1], Z, 0, 0, 0);
    floatx4 n0 = MFMA_BF16(ah0, whi[2][0], Z, 0, 0, 0);
    floatx4 n1 = MFMA_BF16(ah1, whi[2][1], Z, 0, 0, 0);
    r0 = MFMA_BF16(ah2, whi[0][2], r0, 0, 0, 0);
    r1 = MFMA_BF16(ah3, whi[0][3], r1, 0, 0, 0);
    z0 = MFMA_BF16(ah2, whi[1][2], z0, 0, 0, 0);
    z1 = MFMA_BF16(ah3, whi[1][3], z1, 0, 0, 0);
    n0 = MFMA_BF16(ah2, whi[2][2], n0, 0, 0, 0);
    n1 = MFMA_BF16(ah3, whi[2][3], n1, 0, 0, 0);
    __builtin_amdgcn_s_setprio(0);

    // C reg 0 = batch row quad, column j. r,z sigmoids overlap n-chain drain.
    const float pr = fmaf(xt, wi_r, c_r) + (r0[0] + r1[0]);
    const float pz = fmaf(xt, wi_z, c_z) + (z0[0] + z1[0]);
    const float rg = __builtin_amdgcn_rcpf(1.0f + __expf(-pr));
    const float zg = __builtin_amdgcn_rcpf(1.0f + __expf(-pz));
    const float pn = fmaf(rg, (n0[0] + n1[0]) + bh_n, fmaf(xt, wi_n, bi_n));
    const float ng = 1.0f - 2.0f * __builtin_amdgcn_rcpf(1.0f + __expf(2.0f * pn));
    h = fmaf(zg, h - ng, ng);          // z*h + (1-z)*n

    // packed bf16x2 store: DPP quad_perm [1,0,3,2] brings neighbor col's h;
    // cvt_pk (RNE, == bf16_of) packs [j | j+1]; even lanes store one dword.
    // Banks: quad*80 + wv*8 + nn/2 mod 32 -> 2 lanes/bank (free).
    const float hnb = __int_as_float(
        __builtin_amdgcn_mov_dpp(__float_as_int(h), 0xB1, 0xF, 0xF, true));
    int hp;
    asm("v_cvt_pk_bf16_f32 %0, %1, %2" : "=v"(hp) : "v"(h), "v"(hnb));
    if (wlane) *(int*)(nx + w_off) = hp;
  };

  for (int t = 0; t < SEQ_T; t += 2) {
    const float xa = xs[t][quad];       // hoisted off the critical path
    const float xb = xs[t + 1][quad];   // xs is read-only in the loop
    step(hb[0], hb[1], xa);
    __syncthreads();
    step(hb[1], hb[0], xb);
    __syncthreads();
  }

  // epilogue: logits = h @ Wfc^T + bfc (fp32), 4 rows x 10 outs
  hfin[quad][j] = h;
  __syncthreads();
  if (tid < 40) {
    const int r = tid / 10, o = tid - r * 10;
    float acc = bfc[o];
    #pragma unroll 4
    for (int k = 0; k < HID; ++k)
      acc = fmaf(hfin[r][k], Wfc[o * HID + k], acc);
    out[(size_t)(b0 + r) * 10 + o] = acc;
  }
}

extern "C" void kernel_launch(void* const* d_in, const int* in_sizes, int n_in,
                              void* d_out, int out_size, void* d_ws, size_t ws_size,
                              hipStream_t stream) {
  const float* x   = (const float*)d_in[0];
  const float* Wi  = (const float*)d_in[1];
  const float* bi  = (const float*)d_in[2];
  const float* Wh  = (const float*)d_in[3];
  const float* bh  = (const float*)d_in[4];
  const float* Wfc = (const float*)d_in[5];
  const float* bfc = (const float*)d_in[6];
  hipLaunchKernelGGL(gru_sparse4_t, dim3(256), dim3(512), 0, stream,
                     x, Wi, bi, Wh, bh, Wfc, bfc, (float*)d_out);
}